// Round 1
// baseline (2999.316 us; speedup 1.0000x reference)
//
#include <hip/hip_runtime.h>
#include <math.h>

// Problem dims
#define NB     64        // batch
#define NT     32        // T
#define NSTEP  31        // decode steps
#define EMB    300
#define HID    512
#define G3     1536      // 3*HID
#define VOCAB  32000
#define FEATV  2048
#define FEATT  2052

// ---------------- ws layout (float elements) ----------------
#define OFF_WTIH 0                          // w_ih^T  [300][1536]
#define SZ_WTIH  (EMB * G3)
#define OFF_WTHH (OFF_WTIH + SZ_WTIH)       // w_hh^T  [512][1536]
#define SZ_WTHH  (HID * G3)
#define OFF_PWH0 (OFF_WTHH + SZ_WTHH)       // h0 split-K partials [20][64][512]
#define SZ_PWH0  (20 * NB * HID)
#define OFF_H0   (OFF_PWH0 + SZ_PWH0)       // h0 [64][512]
#define SZ_H0    (NB * HID)
#define OFF_XG   (OFF_H0 + SZ_H0)           // x_gates [1984][1536]
#define SZ_XG    (NB * NSTEP * G3)
#define OFF_HS   (OFF_XG + SZ_XG)           // hs [1984][512]
#define SZ_HS    (NB * NSTEP * HID)

__device__ __forceinline__ float sigmoidf_(float x) {
    return 1.0f / (1.0f + expf(-x));
}

// ---------------------------------------------------------------------------
// Tiled transpose: src[R][C] -> dst[C][R]
// grid (ceil(C/32), ceil(R/32)), block (32,8)
// ---------------------------------------------------------------------------
__global__ void transpose_k(const float* __restrict__ src, float* __restrict__ dst,
                            int R, int C) {
    __shared__ float tile[32][33];
    int cb = blockIdx.x * 32, rb = blockIdx.y * 32;
    int tx = threadIdx.x, ty = threadIdx.y;
#pragma unroll
    for (int i = 0; i < 4; i++) {
        int r = rb + ty + i * 8, c = cb + tx;
        if (r < R && c < C) tile[ty + i * 8][tx] = src[r * C + c];
    }
    __syncthreads();
#pragma unroll
    for (int i = 0; i < 4; i++) {
        int c = cb + ty + i * 8, r = rb + tx;
        if (c < C && r < R) dst[c * R + r] = tile[tx][ty + i * 8];
    }
}

// ---------------------------------------------------------------------------
// h0 split-K partial GEMM: feats[64][4100] @ W_map[4100][512]
// grid (8 m-tiles, 20 k-chunks of 205), block (128, 2)
// Each block: m-tile 8, all 512 j, k-chunk 205. Deterministic (no atomics).
// ---------------------------------------------------------------------------
__global__ void h0_partial_k(const float* __restrict__ vis, const float* __restrict__ tgt,
                             const float* __restrict__ Wmap, float* __restrict__ pwh0) {
    __shared__ float fT[205][12];  // [k][m], stride 12 keeps float4 alignment
    int mb = blockIdx.x, ks = blockIdx.y;
    int tid = threadIdx.y * 128 + threadIdx.x;

    for (int i = tid; i < 205 * 8; i += 256) {
        int kk = i / 8, mm = i % 8;
        int k = ks * 205 + kk, b = mb * 8 + mm;
        float v = (k < FEATV) ? vis[b * FEATV + k] : tgt[b * FEATT + (k - FEATV)];
        fT[kk][mm] = v;
    }
    __syncthreads();

    int j = threadIdx.x * 4;        // 128 threads * 4 = all 512 j
    int ty = threadIdx.y;           // 2 groups of 4 m
    float4 acc[4];
#pragma unroll
    for (int mi = 0; mi < 4; mi++) acc[mi] = make_float4(0.f, 0.f, 0.f, 0.f);

    for (int kk = 0; kk < 205; kk++) {
        float4 w4 = *(const float4*)&Wmap[(ks * 205 + kk) * HID + j];
        float4 f4 = *(const float4*)&fT[kk][ty * 4];
        float fm[4] = {f4.x, f4.y, f4.z, f4.w};
#pragma unroll
        for (int mi = 0; mi < 4; mi++) {
            acc[mi].x = fmaf(fm[mi], w4.x, acc[mi].x);
            acc[mi].y = fmaf(fm[mi], w4.y, acc[mi].y);
            acc[mi].z = fmaf(fm[mi], w4.z, acc[mi].z);
            acc[mi].w = fmaf(fm[mi], w4.w, acc[mi].w);
        }
    }
#pragma unroll
    for (int mi = 0; mi < 4; mi++) {
        int m = mb * 8 + ty * 4 + mi;
        *(float4*)&pwh0[(ks * NB + m) * HID + j] = acc[mi];
    }
}

// h0 finish: sum 20 partials + bias, ReLU.  grid 128, block 256
__global__ void h0_finish_k(const float* __restrict__ pwh0, const float* __restrict__ bmap,
                            float* __restrict__ h0) {
    int i = blockIdx.x * 256 + threadIdx.x;   // [0, 32768)
    int j = i & (HID - 1);
    float s = bmap[j];
#pragma unroll
    for (int ks = 0; ks < 20; ks++) s += pwh0[ks * (NB * HID) + i];
    h0[i] = fmaxf(s, 0.f);
}

// ---------------------------------------------------------------------------
// x_gates: embs[1984][300] @ w_ih^T[300][1536] + b_ih
// grid (62 m-tiles, 6 g-tiles), block 256. m-tile 32, g-tile 256.
// thread: 8 m x 4 g (float4). m-fast grid order for wTih L2 reuse.
// ---------------------------------------------------------------------------
__global__ void xg_k(const float* __restrict__ we, const float* __restrict__ wTih,
                     const float* __restrict__ bih, float* __restrict__ xg) {
    __shared__ float embT[EMB][36];   // [k][m], stride 36 (float4-aligned)
    int mb = blockIdx.x, gb = blockIdx.y;
    int tid = threadIdx.x;

    for (int i = tid; i < 32 * EMB; i += 256) {
        int mm = i / EMB, k = i % EMB;
        int m = mb * 32 + mm, b = m / NSTEP, t = m % NSTEP;
        embT[k][mm] = we[(b * NT + t) * EMB + k];
    }
    __syncthreads();

    int vt = tid & 63, ty = tid >> 6;
    int g = gb * 256 + vt * 4;
    float4 bias = *(const float4*)&bih[g];
    float4 acc[8];
#pragma unroll
    for (int mi = 0; mi < 8; mi++) acc[mi] = bias;

    for (int k = 0; k < EMB; k++) {
        float4 w4 = *(const float4*)&wTih[k * G3 + g];
        float4 hA = *(const float4*)&embT[k][ty * 8];
        float4 hB = *(const float4*)&embT[k][ty * 8 + 4];
        float hm[8] = {hA.x, hA.y, hA.z, hA.w, hB.x, hB.y, hB.z, hB.w};
#pragma unroll
        for (int mi = 0; mi < 8; mi++) {
            acc[mi].x = fmaf(hm[mi], w4.x, acc[mi].x);
            acc[mi].y = fmaf(hm[mi], w4.y, acc[mi].y);
            acc[mi].z = fmaf(hm[mi], w4.z, acc[mi].z);
            acc[mi].w = fmaf(hm[mi], w4.w, acc[mi].w);
        }
    }
#pragma unroll
    for (int mi = 0; mi < 8; mi++) {
        int m = mb * 32 + ty * 8 + mi;
        *(float4*)&xg[m * G3 + g] = acc[mi];
    }
}

// ---------------------------------------------------------------------------
// One GRU step: hg = h_prev @ w_hh^T + b_hh; gates; h_new -> hs[:, t, :]
// grid (32 j-slices, 4 b-groups), block 256 = 16 b x 16 j (one pair/thread).
// w_hh^T k-major: per-k reads are 64B-coalesced L2 hits.
// ---------------------------------------------------------------------------
__global__ void gru_k(const float* __restrict__ hprev, int bstride,
                      const float* __restrict__ xg, const float* __restrict__ wThh,
                      const float* __restrict__ bhh, float* __restrict__ hs, int t) {
    __shared__ float hL[16][520];   // b-tile rows, stride 520 (f4-aligned, bank-spread)
    int js = blockIdx.x, bg = blockIdx.y;
    int tid = threadIdx.x;

    for (int i = tid; i < 16 * 128; i += 256) {
        int row = i >> 7, k4 = (i & 127) << 2;
        *(float4*)&hL[row][k4] =
            *(const float4*)&hprev[(size_t)(bg * 16 + row) * bstride + k4];
    }
    __syncthreads();

    int j_i = tid & 15, b_i = tid >> 4;
    int j = js * 16 + j_i;
    int b = bg * 16 + b_i;

    float ar = 0.f, az = 0.f, an = 0.f;
    for (int k4 = 0; k4 < HID; k4 += 4) {
        float4 h4 = *(const float4*)&hL[b_i][k4];
        float hk[4] = {h4.x, h4.y, h4.z, h4.w};
#pragma unroll
        for (int u = 0; u < 4; u++) {
            const float* wrow = &wThh[(size_t)(k4 + u) * G3];
            ar = fmaf(hk[u], wrow[j], ar);
            az = fmaf(hk[u], wrow[HID + j], az);
            an = fmaf(hk[u], wrow[2 * HID + j], an);
        }
    }

    float hr = ar + bhh[j];
    float hz = az + bhh[HID + j];
    float hn = an + bhh[2 * HID + j];
    const float* xrow = &xg[(size_t)(b * NSTEP + t) * G3];
    float xr = xrow[j], xz = xrow[HID + j], xn = xrow[2 * HID + j];

    float r = sigmoidf_(xr + hr);
    float z = sigmoidf_(xz + hz);
    float n = tanhf(xn + r * hn);
    float hp = hL[b_i][j];
    hs[(size_t)(b * NSTEP + t) * HID + j] = (1.f - z) * n + z * hp;
}

// ---------------------------------------------------------------------------
// Classifier: hs[1984][512] @ W_cls[512][32000] + b_cls -> out
// grid (62 m-tiles FAST, 125 v-tiles), block 256. m-tile 32, v-tile 256.
// thread: 8 m x 4 v. hs tile in LDS as hT[k4][m][4] (all reads broadcast b128).
// ---------------------------------------------------------------------------
__global__ void cls_k(const float* __restrict__ hs, const float* __restrict__ Wc,
                      const float* __restrict__ bc, float* __restrict__ out) {
    __shared__ float hT[128][32][4];   // 64 KB: hT[k4][mm][u] = hs[m][4*k4+u]
    int mb = blockIdx.x, vb = blockIdx.y;
    int tid = threadIdx.x;

    for (int i = tid; i < 4096; i += 256) {
        int mm = i & 31, k4 = i >> 5;
        *(float4*)&hT[k4][mm][0] =
            *(const float4*)&hs[(size_t)(mb * 32 + mm) * HID + (k4 << 2)];
    }
    __syncthreads();

    int vt = tid & 63, ty = tid >> 6;
    int v = vb * 256 + vt * 4;
    float4 bias = *(const float4*)&bc[v];
    float4 acc[8];
#pragma unroll
    for (int mi = 0; mi < 8; mi++) acc[mi] = bias;

    for (int k4 = 0; k4 < 128; k4++) {
        const float* wbase = &Wc[(size_t)(k4 << 2) * VOCAB + v];
        float4 w0 = *(const float4*)&wbase[0];
        float4 w1 = *(const float4*)&wbase[VOCAB];
        float4 w2 = *(const float4*)&wbase[2 * VOCAB];
        float4 w3 = *(const float4*)&wbase[3 * VOCAB];
#pragma unroll
        for (int mi = 0; mi < 8; mi++) {
            float4 hm = *(const float4*)&hT[k4][ty * 8 + mi][0];
            acc[mi].x = fmaf(hm.x, w0.x, acc[mi].x);
            acc[mi].y = fmaf(hm.x, w0.y, acc[mi].y);
            acc[mi].z = fmaf(hm.x, w0.z, acc[mi].z);
            acc[mi].w = fmaf(hm.x, w0.w, acc[mi].w);
            acc[mi].x = fmaf(hm.y, w1.x, acc[mi].x);
            acc[mi].y = fmaf(hm.y, w1.y, acc[mi].y);
            acc[mi].z = fmaf(hm.y, w1.z, acc[mi].z);
            acc[mi].w = fmaf(hm.y, w1.w, acc[mi].w);
            acc[mi].x = fmaf(hm.z, w2.x, acc[mi].x);
            acc[mi].y = fmaf(hm.z, w2.y, acc[mi].y);
            acc[mi].z = fmaf(hm.z, w2.z, acc[mi].z);
            acc[mi].w = fmaf(hm.z, w2.w, acc[mi].w);
            acc[mi].x = fmaf(hm.w, w3.x, acc[mi].x);
            acc[mi].y = fmaf(hm.w, w3.y, acc[mi].y);
            acc[mi].z = fmaf(hm.w, w3.z, acc[mi].z);
            acc[mi].w = fmaf(hm.w, w3.w, acc[mi].w);
        }
    }
#pragma unroll
    for (int mi = 0; mi < 8; mi++) {
        int m = mb * 32 + ty * 8 + mi;
        *(float4*)&out[(size_t)m * VOCAB + v] = acc[mi];
    }
}

// ---------------------------------------------------------------------------
extern "C" void kernel_launch(void* const* d_in, const int* in_sizes, int n_in,
                              void* d_out, int out_size, void* d_ws, size_t ws_size,
                              hipStream_t stream) {
    const float* we   = (const float*)d_in[0];   // [64,32,300]
    const float* vis  = (const float*)d_in[1];   // [64,2048]
    const float* tgt  = (const float*)d_in[2];   // [64,2052]
    // d_in[3] = lang_len (unused by the reference math)
    const float* Wmap = (const float*)d_in[4];   // [4100,512]
    const float* bmap = (const float*)d_in[5];   // [512]
    const float* wih  = (const float*)d_in[6];   // [1536,300]
    const float* whh  = (const float*)d_in[7];   // [1536,512]
    const float* bih  = (const float*)d_in[8];   // [1536]
    const float* bhh  = (const float*)d_in[9];   // [1536]
    const float* Wc   = (const float*)d_in[10];  // [512,32000]
    const float* bc   = (const float*)d_in[11];  // [32000]
    float* out = (float*)d_out;
    float* ws  = (float*)d_ws;

    float* wTih  = ws + OFF_WTIH;
    float* wThh  = ws + OFF_WTHH;
    float* pwh0  = ws + OFF_PWH0;
    float* h0buf = ws + OFF_H0;
    float* xg    = ws + OFF_XG;
    float* hsbuf = ws + OFF_HS;

    // 1) Transpose recurrent/input weights to k-major
    transpose_k<<<dim3(10, 48), dim3(32, 8), 0, stream>>>(wih, wTih, G3, EMB);
    transpose_k<<<dim3(16, 48), dim3(32, 8), 0, stream>>>(whh, wThh, G3, HID);

    // 2) h0 = ReLU(concat(vis,tgt) @ W_map + b_map), deterministic split-K
    h0_partial_k<<<dim3(8, 20), dim3(128, 2), 0, stream>>>(vis, tgt, Wmap, pwh0);
    h0_finish_k<<<dim3(128), dim3(256), 0, stream>>>(pwh0, bmap, h0buf);

    // 3) x_gates = embs @ w_ih^T + b_ih
    xg_k<<<dim3(62, 6), dim3(256), 0, stream>>>(we, wTih, bih, xg);

    // 4) GRU scan, 31 steps
    for (int t = 0; t < NSTEP; t++) {
        const float* hprev = (t == 0) ? h0buf : (hsbuf + (size_t)(t - 1) * HID);
        int bstride = (t == 0) ? HID : (NSTEP * HID);
        gru_k<<<dim3(32, 4), dim3(256), 0, stream>>>(hprev, bstride, xg, wThh,
                                                     bhh, hsbuf, t);
    }

    // 5) logits = hs @ W_cls + b_cls
    cls_k<<<dim3(62, 125), dim3(256), 0, stream>>>(hsbuf, Wc, bc, out);
}

// Round 2
// 1195.729 us; speedup vs baseline: 2.5084x; 2.5084x over previous
//
#include <hip/hip_runtime.h>
#include <math.h>

// Problem dims
#define NB     64
#define NT     32
#define NSTEP  31
#define EMB    300
#define HID    512
#define G3     1536
#define VOCAB  32000
#define FEATV  2048
#define FEATT  2052
#define MPAD   2048      // padded M for MFMA classifier (1984 real rows)

// ---------------- ws layout (float-slot offsets, 16B-aligned) ----------------
// Phase A (through GRU): HSBF | WTIH | WPACK | H0 | HS | XG(pwh0 aliased)
// Phase B (classifier):  HSBF | WCB (aliases WTIH..XG, all dead by then)
#define OFF_HSBF 0
#define SZ_HSBF  (MPAD * HID / 2)            // 2048x512 bf16 = 524288 float slots
#define OFF_WTIH (OFF_HSBF + SZ_HSBF)        // w_ih^T [300][1536]
#define SZ_WTIH  (EMB * G3)
#define OFF_WPACK (OFF_WTIH + SZ_WTIH)       // wPack [512][512][4]
#define SZ_WPACK (HID * HID * 4)
#define OFF_H0   (OFF_WPACK + SZ_WPACK)
#define SZ_H0    (NB * HID)
#define OFF_HS   (OFF_H0 + SZ_H0)            // hs [1984][512] f32
#define SZ_HS    (NB * NSTEP * HID)
#define OFF_XG   (OFF_HS + SZ_HS)            // x_gates [1984][1536]; pwh0 aliased here
#define SZ_XG    (NB * NSTEP * G3)
#define WS_A_END (OFF_XG + SZ_XG)
#define OFF_WCB  (OFF_HSBF + SZ_HSBF)        // W_cls^T bf16 [32000][512]
#define SZ_WCB   (VOCAB * HID / 2)           // 8192000 float slots
#define WS_B_END (OFF_WCB + SZ_WCB)          // 8716288 fl = 34.9 MB

typedef __attribute__((ext_vector_type(8))) short short8v;
typedef __attribute__((ext_vector_type(4))) float float4v;

__device__ __forceinline__ float sigmoidf_(float x) {
    return 1.0f / (1.0f + expf(-x));
}

__device__ __forceinline__ unsigned short f2bf(float x) {
    union { float f; unsigned int u; } v; v.f = x;
    unsigned int r = v.u + 0x7FFF + ((v.u >> 16) & 1);  // RNE
    return (unsigned short)(r >> 16);
}

// async global->LDS, 16B per lane; LDS dst = uniform base + lane*16
__device__ __forceinline__ void gld_lds16(const void* g, void* l) {
    __builtin_amdgcn_global_load_lds(
        (const __attribute__((address_space(1))) unsigned int*)g,
        (__attribute__((address_space(3))) unsigned int*)l, 16, 0, 0);
}

// ---------------------------------------------------------------------------
// Tiled transpose: src[R][C] f32 -> dst[C][R] f32 (used for w_ih)
// ---------------------------------------------------------------------------
__global__ void transpose_k(const float* __restrict__ src, float* __restrict__ dst,
                            int R, int C) {
    __shared__ float tile[32][33];
    int cb = blockIdx.x * 32, rb = blockIdx.y * 32;
    int tx = threadIdx.x, ty = threadIdx.y;
#pragma unroll
    for (int i = 0; i < 4; i++) {
        int r = rb + ty + i * 8, c = cb + tx;
        if (r < R && c < C) tile[ty + i * 8][tx] = src[r * C + c];
    }
    __syncthreads();
#pragma unroll
    for (int i = 0; i < 4; i++) {
        int c = cb + ty + i * 8, r = rb + tx;
        if (c < C && r < R) dst[c * R + r] = tile[tx][ty + i * 8];
    }
}

// ---------------------------------------------------------------------------
// Pack w_hh [3*512][512] -> wPack[k][j][4] = {w_r[j][k], w_z[j][k], w_n[j][k], 0}
// thread = (k = idx>>9, j = idx&511): writes fully coalesced float4
// ---------------------------------------------------------------------------
__global__ void pack_whh_k(const float* __restrict__ whh, float* __restrict__ wPack) {
    int idx = blockIdx.x * 256 + threadIdx.x;     // 262144 total
    int k = idx >> 9, j = idx & 511;
    float g0 = whh[(size_t)(0 * HID + j) * HID + k];
    float g1 = whh[(size_t)(1 * HID + j) * HID + k];
    float g2 = whh[(size_t)(2 * HID + j) * HID + k];
    *(float4*)&wPack[(size_t)idx * 4] = make_float4(g0, g1, g2, 0.f);
}

// ---------------------------------------------------------------------------
// h0 split-K partial GEMM (unchanged)
// ---------------------------------------------------------------------------
__global__ void h0_partial_k(const float* __restrict__ vis, const float* __restrict__ tgt,
                             const float* __restrict__ Wmap, float* __restrict__ pwh0) {
    __shared__ float fT[205][12];
    int mb = blockIdx.x, ks = blockIdx.y;
    int tid = threadIdx.y * 128 + threadIdx.x;

    for (int i = tid; i < 205 * 8; i += 256) {
        int kk = i / 8, mm = i % 8;
        int k = ks * 205 + kk, b = mb * 8 + mm;
        float v = (k < FEATV) ? vis[b * FEATV + k] : tgt[b * FEATT + (k - FEATV)];
        fT[kk][mm] = v;
    }
    __syncthreads();

    int j = threadIdx.x * 4;
    int ty = threadIdx.y;
    float4 acc[4];
#pragma unroll
    for (int mi = 0; mi < 4; mi++) acc[mi] = make_float4(0.f, 0.f, 0.f, 0.f);

    for (int kk = 0; kk < 205; kk++) {
        float4 w4 = *(const float4*)&Wmap[(ks * 205 + kk) * HID + j];
        float4 f4 = *(const float4*)&fT[kk][ty * 4];
        float fm[4] = {f4.x, f4.y, f4.z, f4.w};
#pragma unroll
        for (int mi = 0; mi < 4; mi++) {
            acc[mi].x = fmaf(fm[mi], w4.x, acc[mi].x);
            acc[mi].y = fmaf(fm[mi], w4.y, acc[mi].y);
            acc[mi].z = fmaf(fm[mi], w4.z, acc[mi].z);
            acc[mi].w = fmaf(fm[mi], w4.w, acc[mi].w);
        }
    }
#pragma unroll
    for (int mi = 0; mi < 4; mi++) {
        int m = mb * 8 + ty * 4 + mi;
        *(float4*)&pwh0[(ks * NB + m) * HID + j] = acc[mi];
    }
}

__global__ void h0_finish_k(const float* __restrict__ pwh0, const float* __restrict__ bmap,
                            float* __restrict__ h0) {
    int i = blockIdx.x * 256 + threadIdx.x;
    int j = i & (HID - 1);
    float s = bmap[j];
#pragma unroll
    for (int ks = 0; ks < 20; ks++) s += pwh0[ks * (NB * HID) + i];
    h0[i] = fmaxf(s, 0.f);
}

// ---------------------------------------------------------------------------
// x_gates (unchanged)
// ---------------------------------------------------------------------------
__global__ void xg_k(const float* __restrict__ we, const float* __restrict__ wTih,
                     const float* __restrict__ bih, float* __restrict__ xg) {
    __shared__ float embT[EMB][36];
    int mb = blockIdx.x, gb = blockIdx.y;
    int tid = threadIdx.x;

    for (int i = tid; i < 32 * EMB; i += 256) {
        int mm = i / EMB, k = i % EMB;
        int m = mb * 32 + mm, b = m / NSTEP, t = m % NSTEP;
        embT[k][mm] = we[(b * NT + t) * EMB + k];
    }
    __syncthreads();

    int vt = tid & 63, ty = tid >> 6;
    int g = gb * 256 + vt * 4;
    float4 bias = *(const float4*)&bih[g];
    float4 acc[8];
#pragma unroll
    for (int mi = 0; mi < 8; mi++) acc[mi] = bias;

    for (int k = 0; k < EMB; k++) {
        float4 w4 = *(const float4*)&wTih[k * G3 + g];
        float4 hA = *(const float4*)&embT[k][ty * 8];
        float4 hB = *(const float4*)&embT[k][ty * 8 + 4];
        float hm[8] = {hA.x, hA.y, hA.z, hA.w, hB.x, hB.y, hB.z, hB.w};
#pragma unroll
        for (int mi = 0; mi < 8; mi++) {
            acc[mi].x = fmaf(hm[mi], w4.x, acc[mi].x);
            acc[mi].y = fmaf(hm[mi], w4.y, acc[mi].y);
            acc[mi].z = fmaf(hm[mi], w4.z, acc[mi].z);
            acc[mi].w = fmaf(hm[mi], w4.w, acc[mi].w);
        }
    }
#pragma unroll
    for (int mi = 0; mi < 8; mi++) {
        int m = mb * 32 + ty * 8 + mi;
        *(float4*)&xg[m * G3 + g] = acc[mi];
    }
}

// ---------------------------------------------------------------------------
// GRU step v2: thread = (b, j'); wPack float4 per k (coalesced, L1/L2-hot).
// grid (16 js of 32 j', 8 bg of 8 b), block 256.
// ---------------------------------------------------------------------------
__global__ void gru2_k(const float* __restrict__ hprev, int bstride,
                       const float* __restrict__ xg, const float* __restrict__ wPack,
                       const float* __restrict__ bhh, float* __restrict__ hs, int t) {
    __shared__ float hL[8][512];
    int js = blockIdx.x, bg = blockIdx.y;
    int tid = threadIdx.x;

    for (int i = tid; i < 1024; i += 256) {
        int row = i >> 7, k4 = (i & 127) << 2;
        *(float4*)&hL[row][k4] =
            *(const float4*)&hprev[(size_t)(bg * 8 + row) * bstride + k4];
    }
    __syncthreads();

    int tj = tid & 31, tb = tid >> 5;
    int j = js * 32 + tj;
    int b = bg * 8 + tb;

    float ar = 0.f, az = 0.f, an = 0.f;
    const float* wp = wPack + (size_t)j * 4;
    for (int k = 0; k < HID; k += 4) {
        float4 h4 = *(const float4*)&hL[tb][k];
        float4 w0 = *(const float4*)&wp[(size_t)(k + 0) * 2048];
        float4 w1 = *(const float4*)&wp[(size_t)(k + 1) * 2048];
        float4 w2 = *(const float4*)&wp[(size_t)(k + 2) * 2048];
        float4 w3 = *(const float4*)&wp[(size_t)(k + 3) * 2048];
        ar = fmaf(h4.x, w0.x, ar); az = fmaf(h4.x, w0.y, az); an = fmaf(h4.x, w0.z, an);
        ar = fmaf(h4.y, w1.x, ar); az = fmaf(h4.y, w1.y, az); an = fmaf(h4.y, w1.z, an);
        ar = fmaf(h4.z, w2.x, ar); az = fmaf(h4.z, w2.y, az); an = fmaf(h4.z, w2.z, an);
        ar = fmaf(h4.w, w3.x, ar); az = fmaf(h4.w, w3.y, az); an = fmaf(h4.w, w3.z, an);
    }

    float hr = ar + bhh[j];
    float hz = az + bhh[HID + j];
    float hn = an + bhh[2 * HID + j];
    const float* xrow = &xg[(size_t)(b * NSTEP + t) * G3];
    float r = sigmoidf_(xrow[j] + hr);
    float z = sigmoidf_(xrow[HID + j] + hz);
    float n = tanhf(xrow[2 * HID + j] + r * hn);
    float hp = hL[tb][j];
    hs[(size_t)(b * NSTEP + t) * HID + j] = (1.f - z) * n + z * hp;
}

// ---------------------------------------------------------------------------
// Cast hs f32 [1984][512] -> bf16 [2048][512] (pad rows zeroed)
// ---------------------------------------------------------------------------
__global__ void cast_hs_k(const float* __restrict__ hs, unsigned short* __restrict__ hsbf) {
    int i4 = (blockIdx.x * 256 + threadIdx.x) * 4;   // over MPAD*HID
    float4 v = make_float4(0.f, 0.f, 0.f, 0.f);
    if (i4 < NB * NSTEP * HID) v = *(const float4*)&hs[i4];
    uint2 o;
    o.x = (unsigned int)f2bf(v.x) | ((unsigned int)f2bf(v.y) << 16);
    o.y = (unsigned int)f2bf(v.z) | ((unsigned int)f2bf(v.w) << 16);
    *(uint2*)&hsbf[i4] = o;
}

// ---------------------------------------------------------------------------
// Cast+transpose W_cls f32 [512][32000] -> bf16 [32000][512]
// ---------------------------------------------------------------------------
__global__ void transW_k(const float* __restrict__ Wc, unsigned short* __restrict__ Wcb) {
    __shared__ float tile[32][33];
    int nb0 = blockIdx.x * 32, kb0 = blockIdx.y * 32;
    int tx = threadIdx.x, ty = threadIdx.y;
#pragma unroll
    for (int i = 0; i < 4; i++) {
        int k = kb0 + ty + i * 8, n = nb0 + tx;
        tile[ty + i * 8][tx] = Wc[(size_t)k * VOCAB + n];
    }
    __syncthreads();
#pragma unroll
    for (int i = 0; i < 4; i++) {
        int n = nb0 + ty + i * 8, k = kb0 + tx;
        Wcb[(size_t)n * HID + k] = f2bf(tile[tx][ty + i * 8]);
    }
}

// ---------------------------------------------------------------------------
// Classifier MFMA: C[2048][32000] = hsbf[2048][512] @ Wcb^T, + b_cls
// BM=BN=128, BK=64; 4 waves in 2x2; 16x16x32 bf16 MFMA; fragment-ordered LDS
// staged via global_load_lds width=16 (lane-linear => conflict-free b128 reads).
// grid (16 m FAST, 250 n), block 256.
// ---------------------------------------------------------------------------
__global__ __launch_bounds__(256) void cls_mfma_k(
        const unsigned short* __restrict__ hsbf, const unsigned short* __restrict__ Wcb,
        const float* __restrict__ bc, float* __restrict__ out) {
    __shared__ unsigned short Al[8192];   // [g(16)][lane(64)][8 bf16] = 16 KB
    __shared__ unsigned short Bl[8192];
    int mb = blockIdx.x, nb = blockIdx.y;
    int tid = threadIdx.x;
    int lane = tid & 63, w = tid >> 6;
    int wm = w >> 1, wn = w & 1;
    int lr = lane & 15, lq = lane >> 4;    // frag row-within-16, k-quad

    float4v acc[4][4];
#pragma unroll
    for (int i = 0; i < 4; i++)
#pragma unroll
        for (int j = 0; j < 4; j++) acc[i][j] = (float4v)0.f;

    // per-lane source element offsets (k part added per ko)
    for (int ko = 0; ko < 8; ko++) {
#pragma unroll
        for (int ii = 0; ii < 4; ii++) {
            int g = w * 4 + ii;
            int s = g >> 3, mt = g & 7;
            size_t koff = (size_t)(ko * 64 + s * 32 + lq * 8);
            const unsigned short* ga = hsbf + (size_t)(mb * 128 + mt * 16 + lr) * HID + koff;
            gld_lds16(ga, &Al[g * 512]);
            const unsigned short* gb = Wcb + (size_t)(nb * 128 + mt * 16 + lr) * HID + koff;
            gld_lds16(gb, &Bl[g * 512]);
        }
        __syncthreads();
#pragma unroll
        for (int s = 0; s < 2; s++) {
            short8v a[4], bf[4];
#pragma unroll
            for (int i = 0; i < 4; i++)
                a[i] = *(const short8v*)&Al[(s * 8 + wm * 4 + i) * 512 + lane * 8];
#pragma unroll
            for (int j = 0; j < 4; j++)
                bf[j] = *(const short8v*)&Bl[(s * 8 + wn * 4 + j) * 512 + lane * 8];
#pragma unroll
            for (int i = 0; i < 4; i++)
#pragma unroll
                for (int j = 0; j < 4; j++)
                    acc[i][j] = __builtin_amdgcn_mfma_f32_16x16x32_bf16(
                        a[i], bf[j], acc[i][j], 0, 0, 0);
        }
        __syncthreads();
    }

    // epilogue: C/D map col=lane&15, row=(lane>>4)*4+reg
#pragma unroll
    for (int j = 0; j < 4; j++) {
        int n = nb * 128 + wn * 64 + j * 16 + lr;
        float bias = bc[n];
#pragma unroll
        for (int i = 0; i < 4; i++) {
            int mbase = mb * 128 + wm * 64 + i * 16 + lq * 4;
#pragma unroll
            for (int r = 0; r < 4; r++) {
                int m = mbase + r;
                if (m < NB * NSTEP)
                    out[(size_t)m * VOCAB + n] = acc[i][j][r] + bias;
            }
        }
    }
}

// ---------------------------------------------------------------------------
// Fallback fp32 classifier (used only if ws_size too small for bf16 path)
// ---------------------------------------------------------------------------
__global__ void cls_k(const float* __restrict__ hs, const float* __restrict__ Wc,
                      const float* __restrict__ bc, float* __restrict__ out) {
    __shared__ float hT[128][32][4];
    int mb = blockIdx.x, vb = blockIdx.y;
    int tid = threadIdx.x;

    for (int i = tid; i < 4096; i += 256) {
        int mm = i & 31, k4 = i >> 5;
        *(float4*)&hT[k4][mm][0] =
            *(const float4*)&hs[(size_t)(mb * 32 + mm) * HID + (k4 << 2)];
    }
    __syncthreads();

    int vt = tid & 63, ty = tid >> 6;
    int v = vb * 256 + vt * 4;
    float4 bias = *(const float4*)&bc[v];
    float4 acc[8];
#pragma unroll
    for (int mi = 0; mi < 8; mi++) acc[mi] = bias;

    for (int k4 = 0; k4 < 128; k4++) {
        const float* wbase = &Wc[(size_t)(k4 << 2) * VOCAB + v];
        float4 w0 = *(const float4*)&wbase[0];
        float4 w1 = *(const float4*)&wbase[VOCAB];
        float4 w2 = *(const float4*)&wbase[2 * VOCAB];
        float4 w3 = *(const float4*)&wbase[3 * VOCAB];
#pragma unroll
        for (int mi = 0; mi < 8; mi++) {
            float4 hm = *(const float4*)&hT[k4][ty * 8 + mi][0];
            acc[mi].x = fmaf(hm.x, w0.x, acc[mi].x);
            acc[mi].y = fmaf(hm.x, w0.y, acc[mi].y);
            acc[mi].z = fmaf(hm.x, w0.z, acc[mi].z);
            acc[mi].w = fmaf(hm.x, w0.w, acc[mi].w);
            acc[mi].x = fmaf(hm.y, w1.x, acc[mi].x);
            acc[mi].y = fmaf(hm.y, w1.y, acc[mi].y);
            acc[mi].z = fmaf(hm.y, w1.z, acc[mi].z);
            acc[mi].w = fmaf(hm.y, w1.w, acc[mi].w);
            acc[mi].x = fmaf(hm.z, w2.x, acc[mi].x);
            acc[mi].y = fmaf(hm.z, w2.y, acc[mi].y);
            acc[mi].z = fmaf(hm.z, w2.z, acc[mi].z);
            acc[mi].w = fmaf(hm.z, w2.w, acc[mi].w);
            acc[mi].x = fmaf(hm.w, w3.x, acc[mi].x);
            acc[mi].y = fmaf(hm.w, w3.y, acc[mi].y);
            acc[mi].z = fmaf(hm.w, w3.z, acc[mi].z);
            acc[mi].w = fmaf(hm.w, w3.w, acc[mi].w);
        }
    }
#pragma unroll
    for (int mi = 0; mi < 8; mi++) {
        int m = mb * 32 + ty * 8 + mi;
        *(float4*)&out[(size_t)m * VOCAB + v] = acc[mi];
    }
}

// ---------------------------------------------------------------------------
extern "C" void kernel_launch(void* const* d_in, const int* in_sizes, int n_in,
                              void* d_out, int out_size, void* d_ws, size_t ws_size,
                              hipStream_t stream) {
    const float* we   = (const float*)d_in[0];
    const float* vis  = (const float*)d_in[1];
    const float* tgt  = (const float*)d_in[2];
    const float* Wmap = (const float*)d_in[4];
    const float* bmap = (const float*)d_in[5];
    const float* wih  = (const float*)d_in[6];
    const float* whh  = (const float*)d_in[7];
    const float* bih  = (const float*)d_in[8];
    const float* bhh  = (const float*)d_in[9];
    const float* Wc   = (const float*)d_in[10];
    const float* bc   = (const float*)d_in[11];
    float* out = (float*)d_out;
    float* ws  = (float*)d_ws;

    unsigned short* hsbf = (unsigned short*)(ws + OFF_HSBF);
    float* wTih  = ws + OFF_WTIH;
    float* wPack = ws + OFF_WPACK;
    float* h0buf = ws + OFF_H0;
    float* hsbuf = ws + OFF_HS;
    float* xg    = ws + OFF_XG;
    float* pwh0  = ws + OFF_XG;                       // aliased (dead before xg)
    unsigned short* Wcb = (unsigned short*)(ws + OFF_WCB);  // aliases phase-A tail

    bool mfma_path = ws_size >= (size_t)WS_B_END * 4;

    // 1) weight prep
    transpose_k<<<dim3(10, 48), dim3(32, 8), 0, stream>>>(wih, wTih, G3, EMB);
    pack_whh_k<<<dim3(1024), dim3(256), 0, stream>>>(whh, wPack);

    // 2) h0
    h0_partial_k<<<dim3(8, 20), dim3(128, 2), 0, stream>>>(vis, tgt, Wmap, pwh0);
    h0_finish_k<<<dim3(128), dim3(256), 0, stream>>>(pwh0, bmap, h0buf);

    // 3) x_gates (overwrites pwh0 region — after h0_finish)
    xg_k<<<dim3(62, 6), dim3(256), 0, stream>>>(we, wTih, bih, xg);

    // 4) GRU scan
    for (int t = 0; t < NSTEP; t++) {
        const float* hprev = (t == 0) ? h0buf : (hsbuf + (size_t)(t - 1) * HID);
        int bstride = (t == 0) ? HID : (NSTEP * HID);
        gru2_k<<<dim3(16, 8), dim3(256), 0, stream>>>(hprev, bstride, xg, wPack,
                                                      bhh, hsbuf, t);
    }

    // 5) classifier
    if (mfma_path) {
        cast_hs_k<<<dim3(MPAD * HID / 4 / 256), dim3(256), 0, stream>>>(hsbuf, hsbf);
        transW_k<<<dim3(1000, 16), dim3(32, 8), 0, stream>>>(Wc, Wcb);   // clobbers phase-A tail (dead)
        cls_mfma_k<<<dim3(16, 250), dim3(256), 0, stream>>>(hsbf, Wcb, bc, out);
    } else {
        cls_k<<<dim3(62, 125), dim3(256), 0, stream>>>(hsbuf, Wc, bc, out);
    }
}